// Round 7
// baseline (282.611 us; speedup 1.0000x reference)
//
#include <hip/hip_runtime.h>
#include <hip/hip_bf16.h>
#include <math.h>

#define B_     32
#define HID_   768
#define OUT5_  2304
#define HDIM_  512
#define NC_    65536
#define MAXG_  11
#define NL_    670091
#define TOPK_  10
#define CAND_  110   // TOPK_*MAXG_
#define NOUT_  3520  // B_*CAND_
#define CK_    64    // W2 k-rows per staged buffer (stage C)

__device__ __forceinline__ float gelu_exact(float x){
  return 0.5f * x * (1.0f + erff(x * 0.70710678118654752440f));
}

__device__ __forceinline__ unsigned long long packv(float x, int col){
  unsigned u = __float_as_uint(x);
  u = (u & 0x80000000u) ? ~u : (u | 0x80000000u);   // order-preserving float->uint
  return (((unsigned long long)u) << 16) | (unsigned long long)(65535 - col); // tie -> lower col
}

__device__ __forceinline__ float unpack_val(unsigned long long g){
  unsigned u = (unsigned)(g >> 16);
  unsigned bits = (u & 0x80000000u) ? (u & 0x7FFFFFFFu) : ~u;
  return __uint_as_float(bits);
}

__device__ __forceinline__ int unpack_col(unsigned long long g){
  return 65535 - (int)(g & 0xFFFFULL);
}

typedef const __attribute__((address_space(1))) void* gas_t;
typedef __attribute__((address_space(3))) void* las_t;
__device__ __forceinline__ void gload_lds16(const float* g, float* l){
  __builtin_amdgcn_global_load_lds((gas_t)(const void*)g, (las_t)(void*)l, 16, 0, 0);
}

__device__ __forceinline__ void acquire_flag(int* flag, int target){
  if (threadIdx.x == 0){
    while (__hip_atomic_load(flag, __ATOMIC_ACQUIRE, __HIP_MEMORY_SCOPE_AGENT) < target)
      __builtin_amdgcn_s_sleep(4);
  }
  __syncthreads();
}

__device__ __forceinline__ void release_flag(int* flag){
  __syncthreads();                       // all block threads done with stage stores
  if (threadIdx.x == 0){
    __threadfence();                     // agent-scope release (L2 writeback)
    __hip_atomic_fetch_add(flag, 1, __ATOMIC_RELEASE, __HIP_MEMORY_SCOPE_AGENT);
  }
}

__global__ __launch_bounds__(64)
void zero_flags(int* flags){
  if (threadIdx.x < 8) flags[threadIdx.x] = 0;
}

// Persistent megakernel: 256 blocks (1/CU guaranteed -> co-resident) x 512 thr.
// Stages replicate round-4's proven per-thread structures exactly.
__global__ __launch_bounds__(512, 2)
void mega(const float* __restrict__ hidf, const float* __restrict__ hidl5,
          const float* __restrict__ W1, const float* __restrict__ b1,
          const float* __restrict__ W2, const float* __restrict__ b2,
          const float* __restrict__ Wext, const float* __restrict__ bext,
          const float* __restrict__ embed, const int* __restrict__ gy,
          float* __restrict__ logits, float* __restrict__ partial,
          float* __restrict__ hT, float* __restrict__ h_ext,
          float* __restrict__ segv, int* __restrict__ segi,
          float* __restrict__ tk_sc, int* __restrict__ tk_ix,
          int* __restrict__ flags, float* __restrict__ out_f){
  __shared__ float smpool[2][2][CK_ * 128];   // 2 teams x 2 buffers x 32 KB = 128 KB
  __shared__ unsigned long long smx[8];
  const int tid = threadIdx.x;
  const int bid = blockIdx.x;

  // ---------------- Stage A: mlp partials (128 units over blocks 0..63 x 2 teams) ----
  if (bid < 64){
    const int team = tid >> 8, ttid = tid & 255;
    const int u = bid * 2 + team;             // 0..127
    const int x = u & 7, chunk = u >> 3;
    const int jl = ttid & 63, bq = ttid >> 6;
    const int col = x * 64 + jl;
    const float* W; const float* X; int Kfull, k0;
    if (chunk < 4){ W = W1;   X = hidf;  Kfull = HID_;  k0 = chunk * 192; }
    else          { W = Wext; X = hidl5; Kfull = OUT5_; k0 = (chunk - 4) * 192; }
    const float* Wp = W + (size_t)k0 * HDIM_ + col;
    const float* Xp = X + (size_t)(bq * 8) * Kfull + k0;
    float acc[8] = {0,0,0,0,0,0,0,0};
    for (int k = 0; k < 192; ++k){
      float w = Wp[(size_t)k * HDIM_];
      #pragma unroll
      for (int i = 0; i < 8; ++i)
        acc[i] = fmaf(Xp[(size_t)i * Kfull + k], w, acc[i]);
    }
    float* outp = partial + (size_t)chunk * (B_ * HDIM_) + (size_t)(bq * 8) * HDIM_ + col;
    #pragma unroll
    for (int i = 0; i < 8; ++i) outp[(size_t)i * HDIM_] = acc[i];
    release_flag(&flags[0]);
  }

  // ---------------- Stage B: reduce + GELU -> hT, h_ext (blocks 0..63) --------------
  if (bid < 64){
    acquire_flag(&flags[0], 64);
    const int t = bid * 512 + tid;            // 0..32767
    if (t < B_ * HDIM_){
      const int b = t >> 9, j = t & 511;
      float s = b1[j];
      #pragma unroll
      for (int c = 0; c < 4; ++c) s += partial[c * (B_ * HDIM_) + t];
      hT[j * B_ + b] = gelu_exact(s);
    } else {
      const int u2 = t - B_ * HDIM_;
      const int j = u2 & 511;
      float s = bext[j];
      #pragma unroll
      for (int c = 4; c < 16; ++c) s += partial[c * (B_ * HDIM_) + u2];
      h_ext[u2] = gelu_exact(s);
    }
    release_flag(&flags[1]);
  }

  // ---------------- Stage C: staged meta GEMM, 2 stripes/block (teams) --------------
  acquire_flag(&flags[1], 64);
  {
    const int team = tid >> 8, ttid = tid & 255;
    float* smem = &smpool[team][0][0];        // [2][CK_*128]
    const int l  = ttid & 63;
    const int w4 = ttid >> 6;                 // 0..3 within team
    const int colBase = (bid * 2 + team) * 128;
    const int sb8 = __builtin_amdgcn_readfirstlane(w4 * 8);
    const float* __restrict__ hrow = hT + sb8;

    float acc[8][2];
    #pragma unroll
    for (int i = 0; i < 8; ++i){ acc[i][0] = 0.f; acc[i][1] = 0.f; }

    auto stage = [&](int c, int bf){
      const float* gbase = W2 + (size_t)(c * CK_ + w4 * 16 + (l >> 5)) * NC_
                              + colBase + (l & 31) * 4;
      float* lbase = smem + bf * (CK_ * 128) + (w4 * 16) * 128;
      #pragma unroll
      for (int i = 0; i < 8; ++i)
        gload_lds16(gbase + (size_t)(i * 2) * NC_, lbase + i * 2 * 128);
    };

    stage(0, 0);
    __syncthreads();
    int bf = 0;
    for (int c = 0; c < (HDIM_ / CK_); ++c){
      if (c < (HDIM_ / CK_) - 1) stage(c + 1, bf ^ 1);
      const float* hk = hrow + (size_t)(c * CK_) * B_;
      const float* sb = smem + bf * (CK_ * 128);
      #pragma unroll 8
      for (int kk = 0; kk < CK_; ++kk){
        const float w0 = sb[kk * 128 + l];
        const float w1 = sb[kk * 128 + 64 + l];
        const float4 h0 = *reinterpret_cast<const float4*>(hk + (size_t)kk * B_);
        const float4 h1 = *reinterpret_cast<const float4*>(hk + (size_t)kk * B_ + 4);
        acc[0][0] = fmaf(h0.x, w0, acc[0][0]); acc[0][1] = fmaf(h0.x, w1, acc[0][1]);
        acc[1][0] = fmaf(h0.y, w0, acc[1][0]); acc[1][1] = fmaf(h0.y, w1, acc[1][1]);
        acc[2][0] = fmaf(h0.z, w0, acc[2][0]); acc[2][1] = fmaf(h0.z, w1, acc[2][1]);
        acc[3][0] = fmaf(h0.w, w0, acc[3][0]); acc[3][1] = fmaf(h0.w, w1, acc[3][1]);
        acc[4][0] = fmaf(h1.x, w0, acc[4][0]); acc[4][1] = fmaf(h1.x, w1, acc[4][1]);
        acc[5][0] = fmaf(h1.y, w0, acc[5][0]); acc[5][1] = fmaf(h1.y, w1, acc[5][1]);
        acc[6][0] = fmaf(h1.z, w0, acc[6][0]); acc[6][1] = fmaf(h1.z, w1, acc[6][1]);
        acc[7][0] = fmaf(h1.w, w0, acc[7][0]); acc[7][1] = fmaf(h1.w, w1, acc[7][1]);
      }
      __syncthreads();
      bf ^= 1;
    }

    const float bb0 = b2[colBase + l];
    const float bb1 = b2[colBase + 64 + l];
    #pragma unroll
    for (int r = 0; r < 8; ++r){
      logits[(size_t)(sb8 + r) * NC_ + colBase + l]      = acc[r][0] + bb0;
      logits[(size_t)(sb8 + r) * NC_ + colBase + 64 + l] = acc[r][1] + bb1;
    }
  }
  release_flag(&flags[2]);

  // ---------------- Stage D1: per-(row, segment) top-10 (256 units) -----------------
  acquire_flag(&flags[2], 256);
  {
    const int b   = bid >> 3;
    const int seg = bid & 7;
    const int lane = tid & 63, w = tid >> 6;
    const float* row = logits + (size_t)b * NC_ + seg * 8192;
    float v[10]; int ix[10];
    #pragma unroll
    for (int r = 0; r < 10; ++r){ v[r] = -INFINITY; ix[r] = -1; }
    for (int s = 0; s < 16; ++s){
      const int j = s * 512 + tid;
      const float x = row[j];
      if (x > v[9]){
        v[9] = x; ix[9] = seg * 8192 + j;
        #pragma unroll
        for (int p = 9; p > 0; --p){
          if (v[p] > v[p-1]){
            float tv = v[p]; v[p] = v[p-1]; v[p-1] = tv;
            int   ti = ix[p]; ix[p] = ix[p-1]; ix[p-1] = ti;
          }
        }
      }
    }
    for (int r = 0; r < 10; ++r){
      unsigned long long mp = (ix[0] >= 0) ? packv(v[0], ix[0]) : 0ULL;
      unsigned long long wm = mp;
      #pragma unroll
      for (int off = 1; off < 64; off <<= 1){
        unsigned long long o = __shfl_xor(wm, off);
        if (o > wm) wm = o;
      }
      if (lane == 0) smx[w] = wm;
      __syncthreads();
      unsigned long long g = smx[0];
      #pragma unroll
      for (int q = 1; q < 8; ++q) if (smx[q] > g) g = smx[q];
      if (mp == g && mp != 0ULL){
        #pragma unroll
        for (int q = 0; q < 9; ++q){ v[q] = v[q+1]; ix[q] = ix[q+1]; }
        v[9] = -INFINITY; ix[9] = -1;
      }
      if (tid == 0){
        segv[bid * 10 + r] = unpack_val(g);
        segi[bid * 10 + r] = unpack_col(g);
      }
      __syncthreads();
    }
  }
  release_flag(&flags[3]);

  // ---------------- Stage D2: merge 80 -> 10 per row (blocks 0..31) -----------------
  if (bid < 32){
    acquire_flag(&flags[3], 256);
    const int lane = tid & 63, w = tid >> 6;
    unsigned long long mp = 0ULL;
    if (tid < 80) mp = packv(segv[bid * 80 + tid], segi[bid * 80 + tid]);
    for (int r = 0; r < 10; ++r){
      unsigned long long wm = mp;
      #pragma unroll
      for (int off = 1; off < 64; off <<= 1){
        unsigned long long o = __shfl_xor(wm, off);
        if (o > wm) wm = o;
      }
      if (lane == 0) smx[w] = wm;
      __syncthreads();
      unsigned long long g = smx[0];
      #pragma unroll
      for (int q = 1; q < 8; ++q) if (smx[q] > g) g = smx[q];
      if (mp == g && mp != 0ULL) mp = 0ULL;   // consumed
      if (tid == 0){
        tk_ix[bid * TOPK_ + r] = unpack_col(g);
        tk_sc[bid * TOPK_ + r] = 1.0f / (1.0f + expf(-unpack_val(g)));
      }
      __syncthreads();
    }
    release_flag(&flags[4]);
  }

  // ---------------- Stage E: candidate gather + dot + outputs ------------------------
  acquire_flag(&flags[4], 32);
  {
    const int w = tid >> 6, lane = tid & 63;
    const int gw = bid * 8 + w;                  // 0..2047
    const unsigned int* gyw = (const unsigned int*)gy;
    const unsigned int probe = gyw[2 * (size_t)(gw * 64 + lane) + 1];
    const bool is64 = (__ballot(probe != 0u) == 0ULL);  // int64 vs int32 group_y
    __hip_bfloat16* outs = (__hip_bfloat16*)(out_f + NOUT_);
    __hip_bfloat16* outm = outs + NOUT_;
    for (int u = gw; u < NOUT_; u += 2048){
      const int b = u / CAND_;
      const int c = u - b * CAND_;
      const int t = c / MAXG_;
      const int g = c - t * MAXG_;
      const int idx = tk_ix[b * TOPK_ + t];
      const size_t li = (size_t)idx * MAXG_ + g;
      const int cand = is64 ? (int)((const long long*)gy)[li] : gy[li];
      const float* erow  = embed + (size_t)cand * HDIM_;
      const float* hrow2 = h_ext + (size_t)b * HDIM_;
      const float4 e0 = reinterpret_cast<const float4*>(erow)[lane];
      const float4 e1 = reinterpret_cast<const float4*>(erow)[lane + 64];
      const float4 h0 = reinterpret_cast<const float4*>(hrow2)[lane];
      const float4 h1 = reinterpret_cast<const float4*>(hrow2)[lane + 64];
      float s = e0.x*h0.x + e0.y*h0.y + e0.z*h0.z + e0.w*h0.w
              + e1.x*h1.x + e1.y*h1.y + e1.z*h1.z + e1.w*h1.w;
      #pragma unroll
      for (int off = 1; off < 64; off <<= 1) s += __shfl_xor(s, off);
      if (lane == 0){
        const float cs   = (s == 0.0f) ? 0.0f : 1.0f / (1.0f + expf(-s));
        const float comb = cs * ((cand != NL_) ? tk_sc[b * TOPK_ + t] : 0.0f);
        const int o = b * CAND_ + c;
        out_f[o] = (float)cand;
        outs[o]  = __float2bfloat16(cs);
        outm[o]  = __float2bfloat16(comb);
      }
    }
  }
}

extern "C" void kernel_launch(void* const* d_in, const int* in_sizes, int n_in,
                              void* d_out, int out_size, void* d_ws, size_t ws_size,
                              hipStream_t stream){
  const float* hidf  = (const float*)d_in[0];
  const float* hidl5 = (const float*)d_in[1];
  const float* W1    = (const float*)d_in[2];
  const float* b1    = (const float*)d_in[3];
  const float* W2    = (const float*)d_in[4];
  const float* b2    = (const float*)d_in[5];
  const float* Wext  = (const float*)d_in[6];
  const float* bext  = (const float*)d_in[7];
  const float* embed = (const float*)d_in[8];
  const int*   gy    = (const int*)d_in[9];
  float* out_f = (float*)d_out;

  int*   flags   = (int*)d_ws;                     // 8 ints (64 B slot)
  float* base    = (float*)d_ws + 16;
  float* logits  = base;                           // [32][65536]
  float* partial = logits + (size_t)B_ * NC_;      // 16 x [32][512]
  float* hT      = partial + 16 * (B_ * HDIM_);    // [512][32]
  float* h_ext   = hT + B_ * HDIM_;                // [32][512]
  float* segv    = h_ext + B_ * HDIM_;             // 2560
  int*   segi    = (int*)(segv + 2560);            // 2560
  float* tk_sc   = (float*)(segi + 2560);          // 320
  int*   tk_ix   = (int*)(tk_sc + 320);            // 320

  zero_flags<<<1, 64, 0, stream>>>(flags);
  mega<<<256, 512, 0, stream>>>(hidf, hidl5, W1, b1, W2, b2, Wext, bext,
                                embed, gy, logits, partial, hT, h_ext,
                                segv, segi, tk_sc, tk_ix, flags, out_f);
}

// Round 8
// 131.012 us; speedup vs baseline: 2.1571x; 2.1571x over previous
//
#include <hip/hip_runtime.h>
#include <hip/hip_bf16.h>
#include <math.h>

#define B_     32
#define HID_   768
#define OUT5_  2304
#define HDIM_  512
#define NC_    65536
#define MAXG_  11
#define NL_    670091
#define TOPK_  10
#define CAND_  110   // TOPK_*MAXG_
#define NOUT_  3520  // B_*CAND_
#define CK_    64    // W2 k-rows per staged buffer
#define NSTR_  512   // 128-col stripes

__device__ __forceinline__ float gelu_exact(float x){
  return 0.5f * x * (1.0f + erff(x * 0.70710678118654752440f));
}

__device__ __forceinline__ unsigned long long packv(float x, int col){
  unsigned u = __float_as_uint(x);
  u = (u & 0x80000000u) ? ~u : (u | 0x80000000u);   // order-preserving float->uint
  return (((unsigned long long)u) << 16) | (unsigned long long)(65535 - col); // tie -> lower col
}

__device__ __forceinline__ float unpack_val(unsigned long long g){
  unsigned u = (unsigned)(g >> 16);
  unsigned bits = (u & 0x80000000u) ? (u & 0x7FFFFFFFu) : ~u;
  return __uint_as_float(bits);
}

__device__ __forceinline__ int unpack_col(unsigned long long g){
  return 65535 - (int)(g & 0xFFFFULL);
}

__device__ __forceinline__ unsigned long long wave_max_u64(unsigned long long m){
  #pragma unroll
  for (int off = 1; off < 64; off <<= 1){
    unsigned long long o = __shfl_xor(m, off);
    if (o > m) m = o;
  }
  return m;
}

typedef const __attribute__((address_space(1))) void* gas_t;
typedef __attribute__((address_space(3))) void* las_t;
__device__ __forceinline__ void gload_lds16(const float* g, float* l){
  __builtin_amdgcn_global_load_lds((gas_t)(const void*)g, (las_t)(void*)l, 16, 0, 0);
}

// ---- K1: partial sums for both small GEMMs (R4, unchanged) ----
__global__ __launch_bounds__(256)
void mlp_partial(const float* __restrict__ hidf, const float* __restrict__ hidl5,
                 const float* __restrict__ W1, const float* __restrict__ Wext,
                 float* __restrict__ partial){
  const int jl  = threadIdx.x & 63;
  const int bq  = threadIdx.x >> 6;
  const int col = blockIdx.x * 64 + jl;
  const int chunk = blockIdx.y;
  const float* W; const float* X; int Kfull, k0;
  if (chunk < 4){ W = W1;   X = hidf;  Kfull = HID_;  k0 = chunk * 192; }
  else          { W = Wext; X = hidl5; Kfull = OUT5_; k0 = (chunk - 4) * 192; }
  const float* Wp = W + (size_t)k0 * HDIM_ + col;
  const float* Xp = X + (size_t)(bq * 8) * Kfull + k0;
  float acc[8] = {0,0,0,0,0,0,0,0};
  for (int k = 0; k < 192; ++k){
    float w = Wp[(size_t)k * HDIM_];
    #pragma unroll
    for (int i = 0; i < 8; ++i)
      acc[i] = fmaf(Xp[(size_t)i * Kfull + k], w, acc[i]);
  }
  float* outp = partial + (size_t)chunk * (B_ * HDIM_) + (size_t)(bq * 8) * HDIM_ + col;
  #pragma unroll
  for (int i = 0; i < 8; ++i) outp[(size_t)i * HDIM_] = acc[i];
}

// ---- K2: reduce + bias + GELU (R4, unchanged) ----
__global__ __launch_bounds__(256)
void act_kernel(const float* __restrict__ partial, const float* __restrict__ b1,
                const float* __restrict__ bext, float* __restrict__ hT,
                float* __restrict__ h_ext){
  const int t = blockIdx.x * 256 + threadIdx.x;
  if (t < B_ * HDIM_){
    const int b = t >> 9, j = t & 511;
    float s = b1[j];
    #pragma unroll
    for (int c = 0; c < 4; ++c) s += partial[c * (B_ * HDIM_) + t];
    hT[j * B_ + b] = gelu_exact(s);
  } else {
    const int u = t - B_ * HDIM_;
    const int j = u & 511;
    float s = bext[j];
    #pragma unroll
    for (int c = 4; c < 16; ++c) s += partial[c * (B_ * HDIM_) + u];
    h_ext[u] = gelu_exact(s);
  }
}

// ---- K3: staged meta GEMM (R4) + per-(row,stripe) packed-max epilogue ----
__global__ __launch_bounds__(256)
void meta_gemm(const float* __restrict__ hT, const float* __restrict__ W2,
               const float* __restrict__ b2, float* __restrict__ logits,
               unsigned long long* __restrict__ blockmax){
  __shared__ float smem[2][CK_ * 128];   // 2 x 32 KB
  const int l   = threadIdx.x & 63;
  const int w   = threadIdx.x >> 6;
  const int colBase = blockIdx.x * 128;
  const int sb8 = __builtin_amdgcn_readfirstlane(w * 8);
  const float* __restrict__ hrow = hT + sb8;

  float acc[8][2];
  #pragma unroll
  for (int i = 0; i < 8; ++i){ acc[i][0] = 0.f; acc[i][1] = 0.f; }

  auto stage = [&](int c, int bf){
    const float* gbase = W2 + (size_t)(c * CK_ + w * 16 + (l >> 5)) * NC_
                            + colBase + (l & 31) * 4;
    float* lbase = &smem[bf][(w * 16) * 128];
    #pragma unroll
    for (int i = 0; i < 8; ++i)
      gload_lds16(gbase + (size_t)(i * 2) * NC_, lbase + i * 2 * 128);
  };

  stage(0, 0);
  __syncthreads();
  int bf = 0;
  for (int c = 0; c < (HDIM_ / CK_); ++c){
    if (c < (HDIM_ / CK_) - 1) stage(c + 1, bf ^ 1);
    const float* hk = hrow + (size_t)(c * CK_) * B_;
    #pragma unroll 8
    for (int kk = 0; kk < CK_; ++kk){
      const float w0 = smem[bf][kk * 128 + l];
      const float w1 = smem[bf][kk * 128 + 64 + l];
      const float4 h0 = *reinterpret_cast<const float4*>(hk + (size_t)kk * B_);
      const float4 h1 = *reinterpret_cast<const float4*>(hk + (size_t)kk * B_ + 4);
      acc[0][0] = fmaf(h0.x, w0, acc[0][0]); acc[0][1] = fmaf(h0.x, w1, acc[0][1]);
      acc[1][0] = fmaf(h0.y, w0, acc[1][0]); acc[1][1] = fmaf(h0.y, w1, acc[1][1]);
      acc[2][0] = fmaf(h0.z, w0, acc[2][0]); acc[2][1] = fmaf(h0.z, w1, acc[2][1]);
      acc[3][0] = fmaf(h0.w, w0, acc[3][0]); acc[3][1] = fmaf(h0.w, w1, acc[3][1]);
      acc[4][0] = fmaf(h1.x, w0, acc[4][0]); acc[4][1] = fmaf(h1.x, w1, acc[4][1]);
      acc[5][0] = fmaf(h1.y, w0, acc[5][0]); acc[5][1] = fmaf(h1.y, w1, acc[5][1]);
      acc[6][0] = fmaf(h1.z, w0, acc[6][0]); acc[6][1] = fmaf(h1.z, w1, acc[6][1]);
      acc[7][0] = fmaf(h1.w, w0, acc[7][0]); acc[7][1] = fmaf(h1.w, w1, acc[7][1]);
    }
    __syncthreads();
    bf ^= 1;
  }

  const float bb0 = b2[colBase + l];
  const float bb1 = b2[colBase + 64 + l];
  #pragma unroll
  for (int r = 0; r < 8; ++r){
    const float v0 = acc[r][0] + bb0;
    const float v1 = acc[r][1] + bb1;
    logits[(size_t)(sb8 + r) * NC_ + colBase + l]      = v0;
    logits[(size_t)(sb8 + r) * NC_ + colBase + 64 + l] = v1;
    unsigned long long k0 = packv(v0, colBase + l);
    unsigned long long k1 = packv(v1, colBase + 64 + l);
    unsigned long long m  = wave_max_u64(k0 > k1 ? k0 : k1);
    if (l == 0) blockmax[(size_t)(sb8 + r) * NSTR_ + blockIdx.x] = m;
  }
}

// ---- K4: fused { stripe-select top-10 | exact top-10 | candidates } ----
// 32 blocks x 1024 thr. Global top-10 of a row is provably inside the 10
// stripes with largest packed block-max (keys are distinct).
__global__ __launch_bounds__(1024)
void topk_cand(const float* __restrict__ logits,
               const unsigned long long* __restrict__ blockmax,
               const int* __restrict__ gy, const float* __restrict__ embed,
               const float* __restrict__ h_ext, float* __restrict__ out_f){
  __shared__ unsigned long long smx[16];
  __shared__ int   win[TOPK_];
  __shared__ int   tk_i[TOPK_];
  __shared__ float tk_s[TOPK_];
  const int b    = blockIdx.x;
  const int tid  = threadIdx.x;
  const int lane = tid & 63;
  const int w    = tid >> 6;                        // 0..15

  // Phase 1: 10 winning stripes from 512 block-max keys.
  unsigned long long mp = (tid < NSTR_) ? blockmax[(size_t)b * NSTR_ + tid] : 0ULL;
  for (int r = 0; r < 10; ++r){
    unsigned long long wm = wave_max_u64(mp);
    if (lane == 0) smx[w] = wm;
    __syncthreads();
    unsigned long long g = smx[0];
    #pragma unroll
    for (int q = 1; q < 16; ++q) if (smx[q] > g) g = smx[q];
    if (mp == g && g != 0ULL) mp = 0ULL;            // unique owner: keys distinct
    if (tid == 0) win[r] = unpack_col(g) >> 7;      // stripe id
    __syncthreads();
  }

  // Phase 2: exact top-10 over the 10 stripes (1280 values, L2-hot).
  unsigned long long v0 = 0ULL, v1 = 0ULL;
  {
    const float* row = logits + (size_t)b * NC_;
    int t = tid;
    if (t < 1280){
      const int col = win[t >> 7] * 128 + (t & 127);
      v0 = packv(row[col], col);
    }
    t = tid + 1024;
    if (t < 1280){
      const int col = win[t >> 7] * 128 + (t & 127);
      const unsigned long long k = packv(row[col], col);
      if (k > v0){ v1 = v0; v0 = k; } else v1 = k;
    }
  }
  for (int r = 0; r < 10; ++r){
    unsigned long long wm = wave_max_u64(v0);
    if (lane == 0) smx[w] = wm;
    __syncthreads();
    unsigned long long g = smx[0];
    #pragma unroll
    for (int q = 1; q < 16; ++q) if (smx[q] > g) g = smx[q];
    if (v0 == g && g != 0ULL){ v0 = v1; v1 = 0ULL; }
    if (tid == 0){
      tk_i[r] = unpack_col(g);
      tk_s[r] = 1.0f / (1.0f + expf(-unpack_val(g)));
    }
    __syncthreads();
  }

  // Phase 3: candidates; wave w handles slots c = w, w+16, ...
  const unsigned int* gyw = (const unsigned int*)gy;
  const unsigned int probe = gyw[2 * (size_t)((b * 16 + w) * 64 + lane) + 1];
  const bool is64 = (__ballot(probe != 0u) == 0ULL);  // int64 vs int32 group_y

  const float* hrow = h_ext + (size_t)b * HDIM_;
  const float4 h0 = reinterpret_cast<const float4*>(hrow)[lane];
  const float4 h1 = reinterpret_cast<const float4*>(hrow)[lane + 64];
  __hip_bfloat16* outs = (__hip_bfloat16*)(out_f + NOUT_);
  __hip_bfloat16* outm = outs + NOUT_;

  for (int c = w; c < CAND_; c += 16){
    const int t = c / MAXG_;
    const int g = c - t * MAXG_;
    const int idx = tk_i[t];
    const size_t li = (size_t)idx * MAXG_ + g;
    const int cand = is64 ? (int)((const long long*)gy)[li] : gy[li];
    const float* erow = embed + (size_t)cand * HDIM_;
    const float4 e0 = reinterpret_cast<const float4*>(erow)[lane];
    const float4 e1 = reinterpret_cast<const float4*>(erow)[lane + 64];
    float s = e0.x*h0.x + e0.y*h0.y + e0.z*h0.z + e0.w*h0.w
            + e1.x*h1.x + e1.y*h1.y + e1.z*h1.z + e1.w*h1.w;
    #pragma unroll
    for (int off = 1; off < 64; off <<= 1) s += __shfl_xor(s, off);
    if (lane == 0){
      const float cs   = (s == 0.0f) ? 0.0f : 1.0f / (1.0f + expf(-s));
      const float comb = cs * ((cand != NL_) ? tk_s[t] : 0.0f);
      const int o = b * CAND_ + c;
      out_f[o] = (float)cand;
      outs[o]  = __float2bfloat16(cs);
      outm[o]  = __float2bfloat16(comb);
    }
  }
}

extern "C" void kernel_launch(void* const* d_in, const int* in_sizes, int n_in,
                              void* d_out, int out_size, void* d_ws, size_t ws_size,
                              hipStream_t stream){
  const float* hidf  = (const float*)d_in[0];
  const float* hidl5 = (const float*)d_in[1];
  const float* W1    = (const float*)d_in[2];
  const float* b1    = (const float*)d_in[3];
  const float* W2    = (const float*)d_in[4];
  const float* b2    = (const float*)d_in[5];
  const float* Wext  = (const float*)d_in[6];
  const float* bext  = (const float*)d_in[7];
  const float* embed = (const float*)d_in[8];
  const int*   gy    = (const int*)d_in[9];
  float* out_f = (float*)d_out;

  float* ws      = (float*)d_ws;
  float* logits  = ws;                          // [32][65536] f32 (8 MiB)
  float* partial = ws;                          // aliased: dead before meta_gemm
  float* hT      = logits + (size_t)B_ * NC_;   // [512][32]
  float* h_ext   = hT + B_ * HDIM_;             // [32][512]
  unsigned long long* blockmax =
      (unsigned long long*)(h_ext + B_ * HDIM_); // [32][512] u64 (128 KB)

  mlp_partial<<<dim3(8, 16), 256, 0, stream>>>(hidf, hidl5, W1, Wext, partial);
  act_kernel <<<128, 256, 0, stream>>>(partial, b1, bext, hT, h_ext);
  meta_gemm  <<<NSTR_, 256, 0, stream>>>(hT, W2, b2, logits, blockmax);
  topk_cand  <<<B_, 1024, 0, stream>>>(logits, blockmax, gy, embed, h_ext, out_f);
}